// Round 1
// baseline (5003.868 us; speedup 1.0000x reference)
//
#include <hip/hip_runtime.h>
#include <hip/hip_bf16.h>
#include <cstdint>
#include <cstddef>

// ---------------- ws layout (float offsets) ----------------
constexpr size_t OFF_MEM    = 0;          // 65536   memory [NB][D]
constexpr size_t OFF_COLSUM = 65536;      // 65*256  per-step column sums of memory
constexpr size_t OFF_MUSUM  = 82176;      // 64*256  per-step column sums of meas
constexpr size_t OFF_SABS   = 98560;      // 64*4    per-step surprise sums (3 frames)
constexpr size_t OFF_DECAY  = 98816;      // 64      per-step decay scalar
constexpr size_t ZERO_END   = 98880;
constexpr size_t OFF_MEAS   = 98880;      // 65536
constexpr size_t OFF_MEANS  = 164416;     // 3*65536
constexpr size_t OFF_VARS   = 361024;     // 3*65536
constexpr size_t OFF_DT     = 557632;     // 64*256  tridiagonal diag (unused now, kept for layout)
constexpr size_t OFF_ET     = 574016;     // 64*256  tridiagonal offdiag (unused now)
constexpr size_t OFF_RHO    = 590400;     // 64*65536 (consumed by k_tri)
constexpr size_t OFF_MN16   = 4784704;    // bf16 mn [64][256][256] = 2097152 floats
constexpr size_t OFF_E16    = 6881856;    // bf16 E  [32000][256]  = 4096000 floats
constexpr size_t WS_FLOATS  = 10977856;   // ~41.9 MiB

#define SEQ_ 64
#define VOCAB_ 32000

typedef __attribute__((ext_vector_type(8))) short bf16x8;
typedef __attribute__((ext_vector_type(4))) float f32x4;

// ---------------- reduction helpers ----------------
__device__ __forceinline__ float wave_sum(float v){
  v += __shfl_xor(v, 32); v += __shfl_xor(v, 16); v += __shfl_xor(v, 8);
  v += __shfl_xor(v, 4);  v += __shfl_xor(v, 2);  v += __shfl_xor(v, 1);
  return v;
}
__device__ __forceinline__ float block_sum(float v, float* red){
  int tid = threadIdx.x;
  v = wave_sum(v);
  if ((tid & 63) == 0) red[tid >> 6] = v;
  __syncthreads();
  float r = red[0] + red[1] + red[2] + red[3];
  __syncthreads();
  return r;
}
__device__ __forceinline__ float block_min(float v, float* red){
  int tid = threadIdx.x;
  v = fminf(v, __shfl_xor(v, 32)); v = fminf(v, __shfl_xor(v, 16));
  v = fminf(v, __shfl_xor(v, 8));  v = fminf(v, __shfl_xor(v, 4));
  v = fminf(v, __shfl_xor(v, 2));  v = fminf(v, __shfl_xor(v, 1));
  if ((tid & 63) == 0) red[tid >> 6] = v;
  __syncthreads();
  float r = fminf(fminf(red[0], red[1]), fminf(red[2], red[3]));
  __syncthreads();
  return r;
}
__device__ __forceinline__ float block_max(float v, float* red){
  int tid = threadIdx.x;
  v = fmaxf(v, __shfl_xor(v, 32)); v = fmaxf(v, __shfl_xor(v, 16));
  v = fmaxf(v, __shfl_xor(v, 8));  v = fmaxf(v, __shfl_xor(v, 4));
  v = fmaxf(v, __shfl_xor(v, 2));  v = fmaxf(v, __shfl_xor(v, 1));
  if ((tid & 63) == 0) red[tid >> 6] = v;
  __syncthreads();
  float r = fmaxf(fmaxf(red[0], red[1]), fmaxf(red[2], red[3]));
  __syncthreads();
  return r;
}

// ---------------- K0: zero state + E -> bf16 ----------------
__global__ __launch_bounds__(256) void k0_init(const float* __restrict__ E, float* __restrict__ ws){
  size_t i = (size_t)blockIdx.x * 256 + threadIdx.x;   // exactly 8,192,000 threads
  if (i < ZERO_END) ws[i] = 0.f;
  __hip_bfloat16* e16 = (__hip_bfloat16*)(ws + OFF_E16);
  e16[i] = __float2bfloat16(E[i]);
}

// ---------------- K2: per-step meas matvec + stats ----------------
__global__ __launch_bounds__(256) void k_meas(const int* __restrict__ tokens,
    const float* __restrict__ E, const float* __restrict__ W,
    const float* __restrict__ mdbp, const float* __restrict__ nsp,
    float* __restrict__ ws, int t){
  __shared__ float xm_s[256];
  __shared__ __align__(16) float part[4][256];
  __shared__ float red[4];
  const int tid = threadIdx.x, n = blockIdx.x;
  const int lane = tid & 63, w = tid >> 6;

  // prologue (redundant per block): mm, novelty, decay, xm
  float cs = ws[OFF_COLSUM + (size_t)t * 256 + tid];
  float mm = cs * (1.0f / 256.0f);
  int tok = tokens[t];
  float xv = E[(size_t)tok * 256 + tid];
  float sdot = block_sum(xv * mm, red);
  float sx2  = block_sum(xv * xv, red);
  float sm2  = block_sum(mm * mm, red);
  float mem_norm = sqrtf(sm2) + 1e-10f;
  float x_norm   = sqrtf(sx2) + 1e-10f;
  float novelty = (mem_norm > 1e-8f) ? (1.0f - sdot / (x_norm * mem_norm)) : 1.0f;
  float sens = fabsf(nsp[0]);
  float z = mdbp[0] - sens * novelty;
  float decay = 1.0f / (1.0f + expf(-z));
  xm_s[tid] = xv + decay * mm;
  if (n == 0 && tid == 0) ws[OFF_DECAY + t] = decay;
  __syncthreads();

  // matvec: wave w covers d in [64w,64w+64), lane covers e = 4*lane..+3
  const float* Wn = W + (size_t)n * 65536 + (size_t)(w * 64) * 256 + 4 * lane;
  float4 acc = {0.f, 0.f, 0.f, 0.f};
  #pragma unroll 8
  for (int dd = 0; dd < 64; ++dd){
    float xmv = xm_s[w * 64 + dd];
    float4 wv = *(const float4*)(Wn + (size_t)dd * 256);
    acc.x = fmaf(xmv, wv.x, acc.x);
    acc.y = fmaf(xmv, wv.y, acc.y);
    acc.z = fmaf(xmv, wv.z, acc.z);
    acc.w = fmaf(xmv, wv.w, acc.w);
  }
  *(float4*)&part[w][4 * lane] = acc;
  __syncthreads();
  float me = part[0][tid] + part[1][tid] + part[2][tid] + part[3][tid];
  ws[OFF_MEAS + (size_t)n * 256 + tid] = me;
  atomicAdd(&ws[OFF_MUSUM + (size_t)t * 256 + tid], me);

  if (t > 0){
    #pragma unroll
    for (int f = 0; f < 3; ++f){
      float mean = ws[OFF_MEANS + (size_t)f * 65536 + (size_t)n * 256 + tid];
      float var  = ws[OFF_VARS  + (size_t)f * 65536 + (size_t)n * 256 + tid];
      float val = fabsf(me - mean) / sqrtf(var + 1e-8f);
      float s = block_sum(val, red);
      if (tid == 0) atomicAdd(&ws[OFF_SABS + (size_t)t * 4 + f], s);
    }
  }
}

// ---------------- K4: per-step state update ----------------
__global__ __launch_bounds__(256) void k_update(float* __restrict__ ws, int t){
  __shared__ float red[4];
  const int tid = threadIdx.x, n = blockIdx.x;
  float s0 = ws[OFF_SABS + (size_t)t * 4 + 0];
  float s1 = ws[OFF_SABS + (size_t)t * 4 + 1];
  float s2 = ws[OFF_SABS + (size_t)t * 4 + 2];
  const float TH = 1.5f * 65536.0f;   // surprise mean < 1.5  <=>  sum < 1.5*65536 (exact: /2^16)
  bool know = (t > 0) && ((s0 < TH) || (s1 < TH) || (s2 < TH));
  float decay = ws[OFF_DECAY + t];
  size_t ne = (size_t)n * 256 + tid;
  float me = ws[OFF_MEAS + ne];
  float mu = ws[OFF_MUSUM + (size_t)t * 256 + tid] * (1.0f / 256.0f);
  const float c5 = 0.59049f;          // 0.9^5 (closed-form equilibrate)
  float eq = c5 * me + (1.0f - c5) * mu;
  float eff = know ? me : eq;

  const float drs[3] = {0.3f, 0.7f, 0.9f};
  #pragma unroll
  for (int f = 0; f < 3; ++f){
    size_t idx = (size_t)f * 65536 + ne;
    if (t == 0){
      ws[OFF_MEANS + idx] = eff;
      ws[OFF_VARS + idx] = 0.1f;
    } else {
      float dr = drs[f];
      float mo = ws[OFF_MEANS + idx], vo = ws[OFF_VARS + idx];
      float um = dr * mo + (1.0f - dr) * eff;
      float uv = dr * vo + (1.0f - dr) * (eff - mo) * (eff - um);
      uv = fmaxf(uv, 1e-8f);
      ws[OFF_MEANS + idx] = um;
      ws[OFF_VARS + idx] = uv;
    }
  }
  float mo = ws[OFF_MEM + ne];
  float mnew = decay * mo + (1.0f - decay) * eff;
  ws[OFF_MEM + ne] = mnew;
  atomicAdd(&ws[OFF_COLSUM + (size_t)(t + 1) * 256 + tid], mnew);

  float nr2 = block_sum(eff * eff, red);
  float rn = sqrtf(nr2) + 1e-10f;
  __hip_bfloat16* mn16 = (__hip_bfloat16*)(ws + OFF_MN16);
  mn16[(size_t)t * 65536 + ne] = __float2bfloat16(eff / rn);
}

// ---------------- K_rho: rho[t] = mn^T mn / NB (fp32 accum from bf16) ----------------
__global__ __launch_bounds__(256) void k_rho(float* __restrict__ ws){
  const int t = blockIdx.x, rb = blockIdx.y, tid = threadIdx.x;
  __shared__ __align__(16) float tile[32][256];
  const __hip_bfloat16* mn16 = (const __hip_bfloat16*)(ws + OFF_MN16);
  float acc[32];
  #pragma unroll
  for (int i = 0; i < 32; ++i) acc[i] = 0.f;
  for (int c = 0; c < 8; ++c){
    __syncthreads();
    for (int j = tid; j < 8192; j += 256){
      int row = j >> 8, col = j & 255;
      tile[row][col] = __bfloat162float(mn16[(size_t)t * 65536 + (size_t)(c * 32 + row) * 256 + col]);
    }
    __syncthreads();
    for (int nl = 0; nl < 32; ++nl){
      float ev = tile[nl][tid];
      #pragma unroll
      for (int q = 0; q < 8; ++q){
        float4 dv = *(const float4*)&tile[nl][rb * 32 + q * 4];
        acc[q * 4 + 0] = fmaf(dv.x, ev, acc[q * 4 + 0]);
        acc[q * 4 + 1] = fmaf(dv.y, ev, acc[q * 4 + 1]);
        acc[q * 4 + 2] = fmaf(dv.z, ev, acc[q * 4 + 2]);
        acc[q * 4 + 3] = fmaf(dv.w, ev, acc[q * 4 + 3]);
      }
    }
  }
  #pragma unroll
  for (int i = 0; i < 32; ++i)
    ws[OFF_RHO + (size_t)t * 65536 + (size_t)(rb * 32 + i) * 256 + tid] = acc[i] * (1.0f / 256.0f);
}

// ---------------- K_tri: Householder tridiagonalization + Sturm bisection, fused ----------------
// 256 threads; thread c holds the FULL column c of the (symmetric) matrix in
// 256 registers (rho row c == column c by symmetry, so loads are contiguous).
// Per step k:
//   B1: ca holds column k (dumped by its owner at end of previous step)
//   phase A: uval_c = (c>k)?ca[c]:0 -> ua; sigma2 partial via wave shuffle
//   B2: all compute sigma2/alpha/u0/beta redundantly; thread k+1 patches ua[k+1]=u0
//   B3: matvec p_c = Mcol_c . u  (thread-local, no cross-half reduce);
//       pa[c] = masked p; s-partials via wave shuffle
//   B4: rank-2 update  M[r][c] -= S1*u_r + S2*p_r  with
//       S1 = beta*p_c - beta^2*s*u_c,  S2 = beta*u_c   (== u w^T + w u^T);
//       owner of column k+1 dumps its updated column into ca
// Degenerate sigma2 -> beta=0 makes the whole step a no-op (uniform, no branch).
// Tail: d/e collected in LDS; Sturm bisection runs in the same kernel.
__global__ __launch_bounds__(256, 1) void k_tri(float* __restrict__ ws, float* __restrict__ out){
  __shared__ __align__(16) float ca[256];   // current column k
  __shared__ __align__(16) float ua[256];   // u
  __shared__ __align__(16) float pa[256];   // masked p = A u
  __shared__ __align__(16) float dd[256];   // tridiagonal diag
  __shared__ __align__(16) float ee[256];   // tridiagonal offdiag
  __shared__ __align__(16) float redA[4];
  __shared__ __align__(16) float redB[4];
  const int t = blockIdx.x, c = threadIdx.x;
  const int lane = c & 63;
  const float* rho = ws + OFF_RHO + (size_t)t * 65536;

  // load my column (== my row, rho is bitwise symmetric) into registers
  float Mreg[256];
  {
    const float* rowp = rho + (size_t)c * 256;
    #pragma unroll
    for (int r = 0; r < 256; r += 4){
      float4 q = *(const float4*)&rowp[r];
      Mreg[r + 0] = q.x; Mreg[r + 1] = q.y; Mreg[r + 2] = q.z; Mreg[r + 3] = q.w;
    }
  }

  // prologue: dump column 0
  if (c == 0){
    #pragma unroll
    for (int r = 0; r < 256; r += 4){
      float4 q; q.x = Mreg[r]; q.y = Mreg[r + 1]; q.z = Mreg[r + 2]; q.w = Mreg[r + 3];
      *(float4*)&ca[r] = q;
    }
  }
  __syncthreads();                                   // B1 (ca = column 0)

  for (int k = 0; k < 254; ++k){
    // ---- phase A: form u (unpatched) + sigma2 partials ----
    float col = ca[c];
    float uval = (c > k) ? col : 0.f;
    ua[c] = uval;
    float sp = wave_sum(uval * uval);
    if (lane == 0) redA[c >> 6] = sp;
    __syncthreads();                                 // B2
    float4 rA = *(const float4*)&redA[0];
    float sigma2 = (rA.x + rA.y) + (rA.z + rA.w);
    float v0 = ca[k + 1];
    float sig = sqrtf(sigma2);
    float alpha = (v0 >= 0.f) ? -sig : sig;
    float u0 = v0 - alpha;
    bool ok = (sigma2 >= 1e-30f);
    float beta = ok ? (2.0f / (sigma2 - v0 * v0 + u0 * u0)) : 0.f;
    if (c == 0){ dd[k] = ca[k]; ee[k] = ok ? alpha : v0; }
    float ucur = uval;
    if (c == k + 1){ ucur = ok ? u0 : 0.f; ua[c] = ucur; }
    __syncthreads();                                 // B3 (u final)

    // ---- matvec: p_c = M[:,c] . u  (fully thread-local) ----
    float a0 = 0.f, a1 = 0.f, a2 = 0.f, a3 = 0.f;
    #pragma unroll
    for (int r = 0; r < 256; r += 4){
      float4 u4 = *(const float4*)&ua[r];
      a0 = fmaf(Mreg[r + 0], u4.x, a0);
      a1 = fmaf(Mreg[r + 1], u4.y, a1);
      a2 = fmaf(Mreg[r + 2], u4.z, a2);
      a3 = fmaf(Mreg[r + 3], u4.w, a3);
    }
    float p = (a0 + a1) + (a2 + a3);
    float pm = (c > k) ? p : 0.f;                    // mask stale rows
    pa[c] = pm;
    float ssp = wave_sum(ucur * p);                  // u^T A u partials
    if (lane == 0) redB[c >> 6] = ssp;
    __syncthreads();                                 // B4 (pa + s)
    float4 rB = *(const float4*)&redB[0];
    float s = (rB.x + rB.y) + (rB.z + rB.w);
    float gamma = 0.5f * beta * beta * s;
    float S1 = fmaf(-2.0f * gamma, ucur, beta * pm); // beta*p_c - beta^2*s*u_c
    float S2 = beta * ucur;

    // ---- rank-2 update, all in registers ----
    #pragma unroll
    for (int r = 0; r < 256; r += 4){
      float4 u4 = *(const float4*)&ua[r];
      float4 p4 = *(const float4*)&pa[r];
      Mreg[r + 0] = fmaf(-S2, p4.x, fmaf(-S1, u4.x, Mreg[r + 0]));
      Mreg[r + 1] = fmaf(-S2, p4.y, fmaf(-S1, u4.y, Mreg[r + 1]));
      Mreg[r + 2] = fmaf(-S2, p4.z, fmaf(-S1, u4.z, Mreg[r + 2]));
      Mreg[r + 3] = fmaf(-S2, p4.w, fmaf(-S1, u4.w, Mreg[r + 3]));
    }
    // next step's owner publishes its freshly updated column
    if (c == k + 1){
      #pragma unroll
      for (int r = 0; r < 256; r += 4){
        float4 q; q.x = Mreg[r]; q.y = Mreg[r + 1]; q.z = Mreg[r + 2]; q.w = Mreg[r + 3];
        *(float4*)&ca[r] = q;
      }
    }
    __syncthreads();                                 // B1' (ca = column k+1; updates done)
  }

  // ---- tail: dd[254], ee[254], dd[255] ----
  if (c == 255) ca[0] = Mreg[255];                   // static index: M[255][255]
  __syncthreads();
  if (c == 0){
    dd[254] = ca[254];  ee[254] = ca[255];
    dd[255] = ca[0];    ee[255] = 0.f;
  }
  __syncthreads();

  // ---- Sturm bisection (folded; one eigenvalue per thread) ----
  float dvv = dd[c];
  float evv = ee[c];
  ua[c] = evv * evv;                                 // e^2
  pa[c] = fabsf(evv);                                // |e|
  __syncthreads();
  float rad = pa[c] + ((c > 0) ? pa[c - 1] : 0.f);
  float glo = block_min(dvv - rad, redA);
  float ghi = block_max(dvv + rad, redA);

  float l = glo, h = ghi;
  for (int it = 0; it < 40; ++it){
    float mid = 0.5f * (l + h);
    float q = dd[0] - mid;
    int cnt = (q < 0.f) ? 1 : 0;
    #pragma unroll 8
    for (int i = 1; i < 256; ++i){
      float qr = __builtin_amdgcn_rcpf(q);
      q = (dd[i] - mid) - ua[i - 1] * qr;
      q = (fabsf(q) < 1e-25f) ? -1e-25f : q;
      cnt += (q < 0.f) ? 1 : 0;
    }
    if (cnt <= c) l = mid; else h = mid;
  }
  float lam = fmaxf(0.5f * (l + h), 1e-12f);
  float ssum = block_sum(lam, redA);
  out[(size_t)SEQ_ * VOCAB_ + (size_t)t * 256 + c] = lam / ssum;
}

// ---------------- K_gemm: logits[t,v] = (1/NB) * sum_n (E[v]·mn_t[n])^2 ----------------
__global__ __launch_bounds__(512) void k_gemm(const float* __restrict__ ws, float* __restrict__ out){
  __shared__ __align__(16) short A_lds[128 * 64];   // E tile [128 v][64 k]
  __shared__ __align__(16) short B_lds[256 * 64];   // mn tile [256 n][64 k]
  __shared__ float pl[8][64];
  const int tid = threadIdx.x;
  const int bx = blockIdx.x, t = blockIdx.y;
  const int lane = tid & 63, w = tid >> 6;
  const int wr = w >> 2, wc = w & 3;
  const int vbase = bx * 128;
  const short* E16 = (const short*)(ws + OFF_E16);
  const short* MN  = (const short*)(ws + OFF_MN16) + (size_t)t * 65536;

  f32x4 acc[4][4];
  #pragma unroll
  for (int i = 0; i < 4; ++i)
    #pragma unroll
    for (int j = 0; j < 4; ++j){ f32x4 z = {0.f, 0.f, 0.f, 0.f}; acc[i][j] = z; }

  const int g = lane >> 4, r16 = lane & 15;
  for (int it = 0; it < 4; ++it){
    const int k0 = it * 64;
    __syncthreads();
    #pragma unroll
    for (int pa = 0; pa < 2; ++pa){
      int ch = pa * 512 + tid;
      int row = ch >> 3, c8 = ch & 7;
      uint4 v = *(const uint4*)(E16 + (size_t)(vbase + row) * 256 + k0 + c8 * 8);
      *(uint4*)&A_lds[row * 64 + c8 * 8] = v;
    }
    #pragma unroll
    for (int pb = 0; pb < 4; ++pb){
      int ch = pb * 512 + tid;
      int row = ch >> 3, c8 = ch & 7;
      uint4 v = *(const uint4*)(MN + (size_t)row * 256 + k0 + c8 * 8);
      *(uint4*)&B_lds[row * 64 + c8 * 8] = v;
    }
    __syncthreads();
    #pragma unroll
    for (int kk = 0; kk < 64; kk += 32){
      bf16x8 af[4], bf[4];
      #pragma unroll
      for (int fm = 0; fm < 4; ++fm)
        af[fm] = *(const bf16x8*)&A_lds[(wr * 64 + fm * 16 + r16) * 64 + kk + g * 8];
      #pragma unroll
      for (int fn = 0; fn < 4; ++fn)
        bf[fn] = *(const bf16x8*)&B_lds[(wc * 64 + fn * 16 + r16) * 64 + kk + g * 8];
      #pragma unroll
      for (int fm = 0; fm < 4; ++fm)
        #pragma unroll
        for (int fn = 0; fn < 4; ++fn)
          acc[fm][fn] = __builtin_amdgcn_mfma_f32_16x16x32_bf16(af[fm], bf[fn], acc[fm][fn], 0, 0, 0);
    }
  }

  // epilogue: square + reduce over n
  float ps[4][4];
  #pragma unroll
  for (int fm = 0; fm < 4; ++fm)
    #pragma unroll
    for (int i = 0; i < 4; ++i){
      float sv = 0.f;
      #pragma unroll
      for (int fn = 0; fn < 4; ++fn){ float v = acc[fm][fn][i]; sv += v * v; }
      sv += __shfl_xor(sv, 1); sv += __shfl_xor(sv, 2);
      sv += __shfl_xor(sv, 4); sv += __shfl_xor(sv, 8);
      ps[fm][i] = sv;
    }
  __syncthreads();
  if (r16 == 0){
    #pragma unroll
    for (int fm = 0; fm < 4; ++fm)
      #pragma unroll
      for (int i = 0; i < 4; ++i)
        pl[w][fm * 16 + g * 4 + i] = ps[fm][i];
  }
  __syncthreads();
  if (tid < 128){
    int rr = tid;
    int wrr = rr >> 6, lr = rr & 63;
    float sum = pl[wrr * 4 + 0][lr] + pl[wrr * 4 + 1][lr] + pl[wrr * 4 + 2][lr] + pl[wrr * 4 + 3][lr];
    out[(size_t)t * VOCAB_ + vbase + rr] = sum * (1.0f / 256.0f);
  }
}

// ---------------- host ----------------
extern "C" void kernel_launch(void* const* d_in, const int* in_sizes, int n_in,
                              void* d_out, int out_size, void* d_ws, size_t ws_size,
                              hipStream_t stream){
  const int*   tokens = (const int*)d_in[0];
  const float* E      = (const float*)d_in[1];
  const float* W      = (const float*)d_in[2];
  const float* mdbp   = (const float*)d_in[3];
  const float* nsp    = (const float*)d_in[4];
  float* out = (float*)d_out;
  float* ws  = (float*)d_ws;
  if (ws_size < WS_FLOATS * sizeof(float)) return;   // insufficient scratch -> clean fail

  k0_init<<<dim3(32000), dim3(256), 0, stream>>>(E, ws);
  for (int t = 0; t < SEQ_; ++t){
    k_meas<<<dim3(256), dim3(256), 0, stream>>>(tokens, E, W, mdbp, nsp, ws, t);
    k_update<<<dim3(256), dim3(256), 0, stream>>>(ws, t);
  }
  k_rho<<<dim3(64, 8), dim3(256), 0, stream>>>(ws);
  k_tri<<<dim3(64), dim3(256), 0, stream>>>(ws, out);
  k_gemm<<<dim3(250, 64), dim3(512), 0, stream>>>(ws, out);
}